// Round 1
// 373.245 us; speedup vs baseline: 1.2005x; 1.2005x over previous
//
#include <hip/hip_runtime.h>
#include <math.h>

#define BB 16384
#define DD 1024
#define RR 64
#define EE 4
#define ER 256   // EE*RR
#define LL 3

#define LDK 40   // gemm2 LDS stride (bf16): 16B-aligned, <=2-way (free)
#define LDM 72   // mix-phase Tt stride

typedef __bf16 bf16x8 __attribute__((ext_vector_type(8)));
typedef float f32x4 __attribute__((ext_vector_type(4)));
typedef unsigned short us;

static __device__ inline us f2b(float f) {   // RNE f32->bf16
    union { float f; unsigned u; } c; c.f = f;
    return (us)((c.u + 0x7FFF + ((c.u >> 16) & 1)) >> 16);
}
static __device__ inline float b2f(us v) {
    union { unsigned u; float f; } c; c.u = ((unsigned)v) << 16;
    return c.f;
}
static __device__ inline float fast_tanh(float x) {
    float t = __expf(2.f * x);               // inf/0 at extremes -> +-1 exactly
    return 1.f - 2.f / (t + 1.f);
}
// async global->LDS, 16B/lane; dst is wave-uniform base, HW writes lane i at base+i*16
static __device__ __forceinline__ void ld_lds16(const us* g, us* l) {
    __builtin_amdgcn_global_load_lds((const __attribute__((address_space(1))) void*)g,
                                     (__attribute__((address_space(3))) void*)l, 16, 0, 0);
}

// generic f32 -> bf16 (4 elems/thread)
__global__ __launch_bounds__(256) void convF2B(const float* __restrict__ s, us* __restrict__ d) {
    int f = (blockIdx.x * 256 + threadIdx.x) * 4;
    float4 v = *(const float4*)&s[f];
    *(ushort4*)&d[f] = make_ushort4(f2b(v.x), f2b(v.y), f2b(v.z), f2b(v.w));
}
// V [le][d][r] f32 -> Vt [le][r][d] bf16
__global__ __launch_bounds__(256) void convV(const float* __restrict__ V, us* __restrict__ Vt) {
    const int le = blockIdx.x;
    const int d0 = blockIdx.y * 64;
    __shared__ float t[64 * 65];
    const int tid = threadIdx.x;
    const float* Vb = V + (size_t)le * DD * RR;
    #pragma unroll
    for (int p = 0; p < 4; ++p) {
        int f = tid + p * 256; int dd = f >> 4; int c = (f & 15) * 4;
        float4 v = *(const float4*)&Vb[(size_t)(d0 + dd) * RR + c];
        t[dd * 65 + c + 0] = v.x; t[dd * 65 + c + 1] = v.y;
        t[dd * 65 + c + 2] = v.z; t[dd * 65 + c + 3] = v.w;
    }
    __syncthreads();
    int r = tid >> 2, dg = (tid & 3) * 16;
    us o[16];
    #pragma unroll
    for (int k = 0; k < 16; ++k) o[k] = f2b(t[(dg + k) * 65 + r]);
    us* dst = Vt + (size_t)le * RR * DD + (size_t)r * DD + d0 + dg;
    #pragma unroll
    for (int q = 0; q < 4; ++q) *(ushort4*)&dst[q * 4] = *(ushort4*)&o[q * 4];
}

// K1 (all experts + fused gating): block = 64 batch rows, 4 waves, wave e owns expert e.
// D_e[r][b] = Vt_e . x^T over K=1024 via 16x16x32 MFMA; staging = global_load_lds dwordx4
// into kc-major granule layout (LDS granule G=(kc,r): addr G*16B -> ds_read_b128 is 2-way
// aliased only), double-buffered so tile t+1 loads fly under tile t compute.
// Gate logits ride along as 1 extra MFMA/wave (gw rows replicated l15&3 -> rows 0-3 valid).
// Epilogue: tanh -> Tt (wave-private LDS) -> t2=tanh(C_e@t1) -> w = softmax_gate * t2.
__global__ __launch_bounds__(256) void gemm1_fused(const us* __restrict__ xb,
                                                   const us* __restrict__ Vt,
                                                   const us* __restrict__ Ce,
                                                   const us* __restrict__ gwb,
                                                   us* __restrict__ w) {
    const int row0 = blockIdx.x * 64;
    const int tid = threadIdx.x;
    const int lane = tid & 63, wave = tid >> 6;
    const int l15 = lane & 15, quad = lane >> 4;
    const int e64 = wave * 64;

    __shared__ __align__(16) union {
        struct { us buf[2][10240]; us gw[4096]; float gates[256]; } s; // 40K stage + 8K gw + 1K gates
        us Tt[4][4608];                                                // 36.9K, overlaps buf only
    } u;

    const us* vsrc = Vt + (size_t)(e64 + lane) * DD;   // Av row r = wave*64+lane (= e*64+r')
    const us* xsrc = xb + (size_t)(row0 + lane) * DD;  // Bx row b = lane

    // stage gw once: granules [kc 0..127][row 0..3]; G = i*256 + wave*64 + lane
    #pragma unroll
    for (int i = 0; i < 2; ++i)
        ld_lds16(gwb + (size_t)(lane & 3) * DD + (i * 64 + wave * 16 + (lane >> 2)) * 8,
                 &u.s.gw[(i * 256 + e64) * 8]);

    auto STAGE = [&](int bi, int k0) {
        us* bb = u.s.buf[bi];
        #pragma unroll
        for (int i = 0; i < 4; ++i)                     // Av: 256 r x 32 k, [kc=i][r] granules
            ld_lds16(vsrc + k0 + i * 8, &bb[(i * 256 + e64) * 8]);
        ld_lds16(xsrc + k0 + wave * 8, &bb[8192 + wave * 512]);  // Bx: [kc=wave][b]
    };

    f32x4 acc[4][4] = {};
    f32x4 accg = {};
    STAGE(0, 0);
    __syncthreads();                                    // drains vmcnt(0): buf0 + gw ready

    for (int t = 0; t < 32; ++t) {
        const int bi = t & 1;
        if (t < 31) STAGE(bi ^ 1, (t + 1) * 32);        // issue next tile before compute
        const us* bc = u.s.buf[bi];
        bf16x8 af[4], bfr[4];
        #pragma unroll
        for (int mt = 0; mt < 4; ++mt)
            af[mt] = *(const bf16x8*)&bc[quad * 2048 + (e64 + mt * 16 + l15) * 8];
        #pragma unroll
        for (int nt = 0; nt < 4; ++nt)
            bfr[nt] = *(const bf16x8*)&bc[8192 + quad * 512 + (nt * 16 + l15) * 8];
        // gate operands: re-read B-frag at nt=wave (avoids runtime-indexed reg array -> scratch)
        bf16x8 bfrg = *(const bf16x8*)&bc[8192 + quad * 512 + (wave * 16 + l15) * 8];
        bf16x8 afg  = *(const bf16x8*)&u.s.gw[(t * 4 + quad) * 32 + (l15 & 3) * 8];
        #pragma unroll
        for (int mt = 0; mt < 4; ++mt)
            #pragma unroll
            for (int nt = 0; nt < 4; ++nt)
                acc[mt][nt] = __builtin_amdgcn_mfma_f32_16x16x32_bf16(af[mt], bfr[nt], acc[mt][nt], 0, 0, 0);
        accg = __builtin_amdgcn_mfma_f32_16x16x32_bf16(afg, bfrg, accg, 0, 0, 0);
        __syncthreads();                                // drains next-tile loads; guards overwrite
    }

    // tanh -> Tt[b][s] bf16, wave-private region (all staging reads done at last barrier)
    us* Tt = u.Tt[wave];
    #pragma unroll
    for (int mt = 0; mt < 4; ++mt)
        #pragma unroll
        for (int nt = 0; nt < 4; ++nt) {
            int b = nt * 16 + l15;
            us o[4];
            #pragma unroll
            for (int i = 0; i < 4; ++i) o[i] = f2b(fast_tanh(acc[mt][nt][i]));
            *(ushort4*)&Tt[b * LDM + mt * 16 + quad * 4] = *(ushort4*)o;
        }
    if (quad == 0) {   // accg rows 0-3 = logits e0..e3 for b = wave*16+l15; softmax here
        float l0 = accg[0], l1 = accg[1], l2 = accg[2], l3 = accg[3];
        float m = fmaxf(fmaxf(l0, l1), fmaxf(l2, l3));
        float g0 = __expf(l0 - m), g1 = __expf(l1 - m);
        float g2 = __expf(l2 - m), g3 = __expf(l3 - m);
        float inv = 1.f / (g0 + g1 + g2 + g3);
        int b = wave * 16 + l15;
        u.s.gates[0 * 64 + b] = g0 * inv; u.s.gates[1 * 64 + b] = g1 * inv;
        u.s.gates[2 * 64 + b] = g2 * inv; u.s.gates[3 * 64 + b] = g3 * inv;
    }
    __syncthreads();

    // t2 = tanh(C_e @ t1); C-frags direct from global bf16 (L2-hot)
    const us* Cb = Ce + (size_t)wave * RR * RR;
    f32x4 acc2[4][4] = {};
    #pragma unroll
    for (int ks = 0; ks < 2; ++ks) {
        bf16x8 af2[4], bf2[4];
        #pragma unroll
        for (int mt = 0; mt < 4; ++mt)
            af2[mt] = *(const bf16x8*)&Cb[(size_t)(mt * 16 + l15) * RR + ks * 32 + quad * 8];
        #pragma unroll
        for (int nt = 0; nt < 4; ++nt)
            bf2[nt] = *(const bf16x8*)&Tt[(nt * 16 + l15) * LDM + ks * 32 + quad * 8];
        #pragma unroll
        for (int mt = 0; mt < 4; ++mt)
            #pragma unroll
            for (int nt = 0; nt < 4; ++nt)
                acc2[mt][nt] = __builtin_amdgcn_mfma_f32_16x16x32_bf16(af2[mt], bf2[nt], acc2[mt][nt], 0, 0, 0);
    }
    #pragma unroll
    for (int mt = 0; mt < 4; ++mt)
        #pragma unroll
        for (int nt = 0; nt < 4; ++nt) {
            int b = nt * 16 + l15;
            float g = u.s.gates[e64 + b];
            us o[4];
            #pragma unroll
            for (int i = 0; i < 4; ++i) o[i] = f2b(g * fast_tanh(acc2[mt][nt][i]));
            *(ushort4*)&w[(size_t)(row0 + b) * ER + e64 + mt * 16 + quad * 4] = *(ushort4*)o;
        }
}

// K2: D[d][b] = U . w^T ; res = x0*(D+bias) + xl(bf16).  Layers 0-1: write xb only (bf16
// residual stream); last layer: write f32 out only. 256 thr, tile 128d x 128b, wave=(dh,bh).
__global__ __launch_bounds__(256) void gemm2_combine(const us* __restrict__ w,
                                                     const us* __restrict__ Ub,
                                                     const float* __restrict__ x0,
                                                     us* __restrict__ xb,
                                                     const float* __restrict__ biasl,
                                                     float* __restrict__ out, int last) {
    const int row0 = blockIdx.x * 128;     // b
    const int d0 = blockIdx.y * 128;       // d
    __shared__ us Au[128 * LDK];
    __shared__ us Bw[128 * LDK];
    const int tid = threadIdx.x;
    const int lane = tid & 63, wave = tid >> 6;
    const int bh = wave & 1, dh = wave >> 1;
    const int l15 = lane & 15, quad = lane >> 4;
    f32x4 acc[4][4] = {};
    for (int step = 0; step < 8; ++step) {
        int e = step >> 1, r0 = (step & 1) * 32;
        #pragma unroll
        for (int p = 0; p < 2; ++p) {      // Au: 128 d x 32 r
            int f = tid + p * 256; int r = f >> 2; int c = (f & 3) * 8;
            *(float4*)&Au[r * LDK + c] = *(const float4*)&Ub[((size_t)e * DD + d0 + r) * RR + r0 + c];
        }
        #pragma unroll
        for (int p = 0; p < 2; ++p) {      // Bw: 128 b x 32 r
            int f = tid + p * 256; int r = f >> 2; int c = (f & 3) * 8;
            *(float4*)&Bw[r * LDK + c] = *(const float4*)&w[(size_t)(row0 + r) * ER + e * 64 + r0 + c];
        }
        __syncthreads();
        bf16x8 af[4], bfr[4];
        #pragma unroll
        for (int mt = 0; mt < 4; ++mt) af[mt] = *(const bf16x8*)&Au[(dh * 64 + mt * 16 + l15) * LDK + quad * 8];
        #pragma unroll
        for (int nt = 0; nt < 4; ++nt) bfr[nt] = *(const bf16x8*)&Bw[(bh * 64 + nt * 16 + l15) * LDK + quad * 8];
        #pragma unroll
        for (int mt = 0; mt < 4; ++mt)
            #pragma unroll
            for (int nt = 0; nt < 4; ++nt)
                acc[mt][nt] = __builtin_amdgcn_mfma_f32_16x16x32_bf16(af[mt], bfr[nt], acc[mt][nt], 0, 0, 0);
        __syncthreads();
    }
    #pragma unroll
    for (int nt = 0; nt < 4; ++nt) {
        int b = row0 + bh * 64 + nt * 16 + l15;
        #pragma unroll
        for (int mt = 0; mt < 4; ++mt) {
            int d = d0 + dh * 64 + mt * 16 + quad * 4;
            size_t base = (size_t)b * DD + d;
            float4 xv = *(const float4*)&x0[base];
            ushort4 xlb = *(const ushort4*)&xb[base];
            float4 bv = *(const float4*)&biasl[d];
            float4 o;
            o.x = xv.x * (acc[mt][nt][0] + bv.x) + b2f(xlb.x);
            o.y = xv.y * (acc[mt][nt][1] + bv.y) + b2f(xlb.y);
            o.z = xv.z * (acc[mt][nt][2] + bv.z) + b2f(xlb.z);
            o.w = xv.w * (acc[mt][nt][3] + bv.w) + b2f(xlb.w);
            if (last) {
                *(float4*)&out[base] = o;
            } else {
                *(ushort4*)&xb[base] = make_ushort4(f2b(o.x), f2b(o.y), f2b(o.z), f2b(o.w));
            }
        }
    }
}

extern "C" void kernel_launch(void* const* d_in, const int* in_sizes, int n_in,
                              void* d_out, int out_size, void* d_ws, size_t ws_size,
                              hipStream_t stream) {
    const float* inputs = (const float*)d_in[0];
    const float* U      = (const float*)d_in[1];
    const float* V      = (const float*)d_in[2];
    const float* C      = (const float*)d_in[3];
    const float* gw     = (const float*)d_in[4];
    const float* bias   = (const float*)d_in[5];
    float* out = (float*)d_out;

    // ws: xb 33.55 MB | w 8.39 | gwb (in old gates slot, 0.26) | Vt 1.57 | Ub 1.57 | Cb 0.10
    us*    xb    = (us*)d_ws;
    us*    wbf   = xb + (size_t)BB * DD;
    float* gsc   = (float*)(wbf + (size_t)BB * ER);
    us*    gwb   = (us*)gsc;                      // 8 KB bf16 gate weights
    us*    Vt    = (us*)(gsc + (size_t)BB * 4);
    us*    Ub    = Vt + (size_t)LL * EE * RR * DD;
    us*    Cb    = Ub + (size_t)LL * EE * DD * RR;

    convF2B<<<dim3(BB * DD / 1024), 256, 0, stream>>>(inputs, xb);
    convF2B<<<dim3(LL * EE * DD * RR / 1024), 256, 0, stream>>>(U, Ub);
    convF2B<<<dim3(LL * EE * RR * RR / 1024), 256, 0, stream>>>(C, Cb);
    convF2B<<<dim3(EE * DD / 1024), 256, 0, stream>>>(gw, gwb);
    convV<<<dim3(LL * EE, DD / 64), 256, 0, stream>>>(V, Vt);

    for (int i = 0; i < LL; ++i) {
        gemm1_fused<<<dim3(BB / 64), 256, 0, stream>>>(
            xb, Vt + (size_t)i * EE * RR * DD, Cb + (size_t)i * EE * RR * RR, gwb, wbf);
        gemm2_combine<<<dim3(BB / 128, DD / 128), 256, 0, stream>>>(
            wbf, Ub + (size_t)i * EE * DD * RR, inputs, xb, bias + (size_t)i * DD,
            out, i == LL - 1);
    }
}

// Round 3
// 325.355 us; speedup vs baseline: 1.3772x; 1.1472x over previous
//
#include <hip/hip_runtime.h>
#include <math.h>

#define BB 16384
#define DD 1024
#define RR 64
#define EE 4
#define ER 256   // EE*RR
#define LL 3

#define LDM 72   // mix-phase Tt stride

typedef __bf16 bf16x8 __attribute__((ext_vector_type(8)));
typedef float f32x4 __attribute__((ext_vector_type(4)));
typedef unsigned short us;

static __device__ inline us f2b(float f) {   // RNE f32->bf16
    union { float f; unsigned u; } c; c.f = f;
    return (us)((c.u + 0x7FFF + ((c.u >> 16) & 1)) >> 16);
}
static __device__ inline float b2f(us v) {
    union { unsigned u; float f; } c; c.u = ((unsigned)v) << 16;
    return c.f;
}
static __device__ inline float fast_tanh(float x) {
    float t = __expf(2.f * x);               // inf/0 at extremes -> +-1 exactly
    return 1.f - 2.f / (t + 1.f);
}
// async global->LDS, 16B/lane; dst is wave-uniform base, HW writes lane i at base+i*16
static __device__ __forceinline__ void ld_lds16(const us* g, us* l) {
    __builtin_amdgcn_global_load_lds((const __attribute__((address_space(1))) void*)g,
                                     (__attribute__((address_space(3))) void*)l, 16, 0, 0);
}

// generic f32 -> bf16 (4 elems/thread)
__global__ __launch_bounds__(256) void convF2B(const float* __restrict__ s, us* __restrict__ d) {
    int f = (blockIdx.x * 256 + threadIdx.x) * 4;
    float4 v = *(const float4*)&s[f];
    *(ushort4*)&d[f] = make_ushort4(f2b(v.x), f2b(v.y), f2b(v.z), f2b(v.w));
}
// V [le][d][r] f32 -> Vt [le][r][d] bf16
__global__ __launch_bounds__(256) void convV(const float* __restrict__ V, us* __restrict__ Vt) {
    const int le = blockIdx.x;
    const int d0 = blockIdx.y * 64;
    __shared__ float t[64 * 65];
    const int tid = threadIdx.x;
    const float* Vb = V + (size_t)le * DD * RR;
    #pragma unroll
    for (int p = 0; p < 4; ++p) {
        int f = tid + p * 256; int dd = f >> 4; int c = (f & 15) * 4;
        float4 v = *(const float4*)&Vb[(size_t)(d0 + dd) * RR + c];
        t[dd * 65 + c + 0] = v.x; t[dd * 65 + c + 1] = v.y;
        t[dd * 65 + c + 2] = v.z; t[dd * 65 + c + 3] = v.w;
    }
    __syncthreads();
    int r = tid >> 2, dg = (tid & 3) * 16;
    us o[16];
    #pragma unroll
    for (int k = 0; k < 16; ++k) o[k] = f2b(t[(dg + k) * 65 + r]);
    us* dst = Vt + (size_t)le * RR * DD + (size_t)r * DD + d0 + dg;
    #pragma unroll
    for (int q = 0; q < 4; ++q) *(ushort4*)&dst[q * 4] = *(ushort4*)&o[q * 4];
}

// K1 (all experts + fused gating): block = 64 b-rows, 4 waves, wave e = expert.
// Staging: global_load_lds dwordx4, LINEAR LDS dst (granule g=(row,slot), addr g*16B),
// SWIZZLED global src (slot = kc ^ ((row&15)>>1 & 3)) -> coalesced 64B-per-row reads AND
// 2-way-only bank aliasing on ds_read_b128 fragment reads. Double-buffered with raw
// s_barrier + counted vmcnt(5) so next-tile DMA stays in flight across the barrier.
// Per-buffer size: Av 256 rows x 4 granules (8192 us) + Bx 64 rows x 4 (2048 us) = 10240 us.
__global__ __launch_bounds__(256) void gemm1_fused(const us* __restrict__ xb,
                                                   const us* __restrict__ Vt,
                                                   const us* __restrict__ Ce,
                                                   const us* __restrict__ gwb,
                                                   us* __restrict__ w) {
    const int row0 = blockIdx.x * 64;
    const int tid = threadIdx.x;
    const int lane = tid & 63, wave = tid >> 6;
    const int l15 = lane & 15, quad = lane >> 4;
    const int e64 = wave * 64;

    __shared__ __align__(16) union {
        struct { us buf[2][10240]; us gw[4096]; float gates[256]; } s;  // 40K + 8K + 1K = 49K
        us Tt[4][4608];                                                 // aliases buf only
    } u;

    const int kcA = (lane & 3) ^ ((lane >> 3) & 3);   // swizzled source chunk
    const int sA  = quad ^ ((l15 >> 1) & 3);          // swizzled read slot

    // gw staged once: granules [kc 0..127][row 0..3]
    #pragma unroll
    for (int i = 0; i < 2; ++i)
        ld_lds16(gwb + (size_t)(lane & 3) * DD + (i * 64 + wave * 16 + (lane >> 2)) * 8,
                 &u.s.gw[(i * 256 + e64) * 8]);

    auto STAGE = [&](int bi, int k0) {
        us* bb = u.s.buf[bi];
        #pragma unroll
        for (int i = 0; i < 4; ++i) {                 // Av: 256 rows (4 experts x 64 r)
            int row = i * 64 + wave * 16 + (lane >> 2);
            ld_lds16(Vt + (size_t)row * DD + k0 + kcA * 8, &bb[i * 2048 + wave * 512]);
        }
        {                                             // Bx: 64 b-rows
            int row = wave * 16 + (lane >> 2);
            ld_lds16(xb + (size_t)(row0 + row) * DD + k0 + kcA * 8, &bb[8192 + wave * 512]);
        }
    };

    f32x4 acc[4][4] = {};
    f32x4 accg = {};
    STAGE(0, 0);

    for (int t = 0; t < 32; ++t) {
        __builtin_amdgcn_s_barrier();                 // prior readers done before overwrite
        if (t < 31) {
            STAGE((t + 1) & 1, (t + 1) * 32);
            asm volatile("s_waitcnt vmcnt(5)" ::: "memory");   // tile t complete (mine)
        } else {
            asm volatile("s_waitcnt vmcnt(0)" ::: "memory");
        }
        __builtin_amdgcn_s_barrier();                 // tile t complete (all waves)
        __builtin_amdgcn_sched_barrier(0);
        const us* bb = u.s.buf[t & 1];
        bf16x8 af[4], bfr[4];
        #pragma unroll
        for (int mt = 0; mt < 4; ++mt)
            af[mt] = *(const bf16x8*)&bb[(e64 + mt * 16 + l15) * 32 + sA * 8];
        #pragma unroll
        for (int nt = 0; nt < 4; ++nt)
            bfr[nt] = *(const bf16x8*)&bb[8192 + (nt * 16 + l15) * 32 + sA * 8];
        bf16x8 bfrg = *(const bf16x8*)&bb[8192 + (wave * 16 + l15) * 32 + sA * 8];
        bf16x8 afg  = *(const bf16x8*)&u.s.gw[(t * 4 + quad) * 32 + (l15 & 3) * 8];
        #pragma unroll
        for (int mt = 0; mt < 4; ++mt)
            #pragma unroll
            for (int nt = 0; nt < 4; ++nt)
                acc[mt][nt] = __builtin_amdgcn_mfma_f32_16x16x32_bf16(af[mt], bfr[nt], acc[mt][nt], 0, 0, 0);
        accg = __builtin_amdgcn_mfma_f32_16x16x32_bf16(afg, bfrg, accg, 0, 0, 0);
    }
    __builtin_amdgcn_s_barrier();                     // all reads done before Tt alias writes

    // tanh -> Tt[b][s] bf16, wave-private region
    us* Tt = u.Tt[wave];
    #pragma unroll
    for (int mt = 0; mt < 4; ++mt)
        #pragma unroll
        for (int nt = 0; nt < 4; ++nt) {
            int b = nt * 16 + l15;
            us o[4];
            #pragma unroll
            for (int i = 0; i < 4; ++i) o[i] = f2b(fast_tanh(acc[mt][nt][i]));
            *(ushort4*)&Tt[b * LDM + mt * 16 + quad * 4] = *(ushort4*)o;
        }
    if (quad == 0) {   // accg rows 0-3 = logits e0..e3 for b = wave*16+l15
        float l0 = accg[0], l1 = accg[1], l2 = accg[2], l3 = accg[3];
        float m = fmaxf(fmaxf(l0, l1), fmaxf(l2, l3));
        float g0 = __expf(l0 - m), g1 = __expf(l1 - m);
        float g2 = __expf(l2 - m), g3 = __expf(l3 - m);
        float inv = 1.f / (g0 + g1 + g2 + g3);
        int b = wave * 16 + l15;
        u.s.gates[0 * 64 + b] = g0 * inv; u.s.gates[1 * 64 + b] = g1 * inv;
        u.s.gates[2 * 64 + b] = g2 * inv; u.s.gates[3 * 64 + b] = g3 * inv;
    }
    __syncthreads();

    // t2 = tanh(C_e @ t1); C-frags direct from global bf16 (L2-hot)
    const us* Cb = Ce + (size_t)wave * RR * RR;
    f32x4 acc2[4][4] = {};
    #pragma unroll
    for (int ks = 0; ks < 2; ++ks) {
        bf16x8 af2[4], bf2[4];
        #pragma unroll
        for (int mt = 0; mt < 4; ++mt)
            af2[mt] = *(const bf16x8*)&Cb[(size_t)(mt * 16 + l15) * RR + ks * 32 + quad * 8];
        #pragma unroll
        for (int nt = 0; nt < 4; ++nt)
            bf2[nt] = *(const bf16x8*)&Tt[(nt * 16 + l15) * LDM + ks * 32 + quad * 8];
        #pragma unroll
        for (int mt = 0; mt < 4; ++mt)
            #pragma unroll
            for (int nt = 0; nt < 4; ++nt)
                acc2[mt][nt] = __builtin_amdgcn_mfma_f32_16x16x32_bf16(af2[mt], bf2[nt], acc2[mt][nt], 0, 0, 0);
    }
    #pragma unroll
    for (int mt = 0; mt < 4; ++mt)
        #pragma unroll
        for (int nt = 0; nt < 4; ++nt) {
            int b = nt * 16 + l15;
            float g = u.s.gates[e64 + b];
            us o[4];
            #pragma unroll
            for (int i = 0; i < 4; ++i) o[i] = f2b(g * fast_tanh(acc2[mt][nt][i]));
            *(ushort4*)&w[(size_t)(row0 + b) * ER + e64 + mt * 16 + quad * 4] = *(ushort4*)o;
        }
}

// K2: D[d][b] = U . w^T ; res = x0*(D+bias) + xl(bf16). 512 thr (8 waves), tile 128d x 128b,
// wave = (dh 0..3, bh 0..1) -> 32d x 64b each. GEMM staged via swizzled-src global_load_lds,
// dbuf + counted vmcnt. Epilogue batch-issues all x0/xb loads for deep MLP.
__global__ __launch_bounds__(512, 4) void gemm2_combine(const us* __restrict__ w,
                                                        const us* __restrict__ Ub,
                                                        const float* __restrict__ x0,
                                                        us* __restrict__ xb,
                                                        const float* __restrict__ biasl,
                                                        float* __restrict__ out, int last) {
    const int row0 = blockIdx.x * 128;     // b
    const int d0 = blockIdx.y * 128;       // d
    __shared__ __align__(16) us sm2[2][8192];   // per buf: Au 128x32 @0, Bw 128x32 @4096
    const int tid = threadIdx.x;
    const int lane = tid & 63, wave = tid >> 6;
    const int bh = wave & 1, dh = wave >> 1;
    const int l15 = lane & 15, quad = lane >> 4;

    const int kcA = (lane & 3) ^ ((lane >> 3) & 3);
    const int sA  = quad ^ ((l15 >> 1) & 3);

    auto STAGE = [&](int bi, int s) {
        int e = s >> 1, r0q = (s & 1) * 32;
        us* bb = sm2[bi];
        int row = wave * 16 + (lane >> 2);            // 0..127
        ld_lds16(Ub + ((size_t)e * DD + d0 + row) * RR + r0q + kcA * 8, &bb[wave * 512]);
        ld_lds16(w + (size_t)(row0 + row) * ER + e * 64 + r0q + kcA * 8, &bb[4096 + wave * 512]);
    };

    f32x4 acc[2][4] = {};
    STAGE(0, 0);
    for (int t = 0; t < 8; ++t) {
        __builtin_amdgcn_s_barrier();
        if (t < 7) {
            STAGE((t + 1) & 1, t + 1);
            asm volatile("s_waitcnt vmcnt(2)" ::: "memory");
        } else {
            asm volatile("s_waitcnt vmcnt(0)" ::: "memory");
        }
        __builtin_amdgcn_s_barrier();
        __builtin_amdgcn_sched_barrier(0);
        const us* bb = sm2[t & 1];
        bf16x8 af[2], bfr[4];
        #pragma unroll
        for (int mt = 0; mt < 2; ++mt)
            af[mt] = *(const bf16x8*)&bb[(dh * 32 + mt * 16 + l15) * 32 + sA * 8];
        #pragma unroll
        for (int nt = 0; nt < 4; ++nt)
            bfr[nt] = *(const bf16x8*)&bb[4096 + (bh * 64 + nt * 16 + l15) * 32 + sA * 8];
        #pragma unroll
        for (int mt = 0; mt < 2; ++mt)
            #pragma unroll
            for (int nt = 0; nt < 4; ++nt)
                acc[mt][nt] = __builtin_amdgcn_mfma_f32_16x16x32_bf16(af[mt], bfr[nt], acc[mt][nt], 0, 0, 0);
    }

    // epilogue: batch-issue all loads first (deep MLP), then compute + store
    float4 xv[2][4]; ushort4 xl[2][4];
    #pragma unroll
    for (int mt = 0; mt < 2; ++mt)
        #pragma unroll
        for (int nt = 0; nt < 4; ++nt) {
            size_t base = (size_t)(row0 + bh * 64 + nt * 16 + l15) * DD
                        + (d0 + dh * 32 + mt * 16 + quad * 4);
            xv[mt][nt] = *(const float4*)&x0[base];
            xl[mt][nt] = *(const ushort4*)&xb[base];
        }
    float4 bv[2];
    #pragma unroll
    for (int mt = 0; mt < 2; ++mt)
        bv[mt] = *(const float4*)&biasl[d0 + dh * 32 + mt * 16 + quad * 4];

    #pragma unroll
    for (int mt = 0; mt < 2; ++mt)
        #pragma unroll
        for (int nt = 0; nt < 4; ++nt) {
            size_t base = (size_t)(row0 + bh * 64 + nt * 16 + l15) * DD
                        + (d0 + dh * 32 + mt * 16 + quad * 4);
            float4 o;
            o.x = xv[mt][nt].x * (acc[mt][nt][0] + bv[mt].x) + b2f(xl[mt][nt].x);
            o.y = xv[mt][nt].y * (acc[mt][nt][1] + bv[mt].y) + b2f(xl[mt][nt].y);
            o.z = xv[mt][nt].z * (acc[mt][nt][2] + bv[mt].z) + b2f(xl[mt][nt].z);
            o.w = xv[mt][nt].w * (acc[mt][nt][3] + bv[mt].w) + b2f(xl[mt][nt].w);
            if (last) {
                *(float4*)&out[base] = o;
            } else {
                *(ushort4*)&xb[base] = make_ushort4(f2b(o.x), f2b(o.y), f2b(o.z), f2b(o.w));
            }
        }
}

extern "C" void kernel_launch(void* const* d_in, const int* in_sizes, int n_in,
                              void* d_out, int out_size, void* d_ws, size_t ws_size,
                              hipStream_t stream) {
    const float* inputs = (const float*)d_in[0];
    const float* U      = (const float*)d_in[1];
    const float* V      = (const float*)d_in[2];
    const float* C      = (const float*)d_in[3];
    const float* gw     = (const float*)d_in[4];
    const float* bias   = (const float*)d_in[5];
    float* out = (float*)d_out;

    // ws: xb 33.55 MB | w 8.39 | gwb (8KB in old gates slot) | Vt 1.57 | Ub 1.57 | Cb 0.10
    us*    xb    = (us*)d_ws;
    us*    wbf   = xb + (size_t)BB * DD;
    float* gsc   = (float*)(wbf + (size_t)BB * ER);
    us*    gwb   = (us*)gsc;
    us*    Vt    = (us*)(gsc + (size_t)BB * 4);
    us*    Ub    = Vt + (size_t)LL * EE * RR * DD;
    us*    Cb    = Ub + (size_t)LL * EE * DD * RR;

    convF2B<<<dim3(BB * DD / 1024), 256, 0, stream>>>(inputs, xb);
    convF2B<<<dim3(LL * EE * DD * RR / 1024), 256, 0, stream>>>(U, Ub);
    convF2B<<<dim3(LL * EE * RR * RR / 1024), 256, 0, stream>>>(C, Cb);
    convF2B<<<dim3(EE * DD / 1024), 256, 0, stream>>>(gw, gwb);
    convV<<<dim3(LL * EE, DD / 64), 256, 0, stream>>>(V, Vt);

    for (int i = 0; i < LL; ++i) {
        gemm1_fused<<<dim3(BB / 64), 256, 0, stream>>>(
            xb, Vt + (size_t)i * EE * RR * DD, Cb + (size_t)i * EE * RR * RR, gwb, wbf);
        gemm2_combine<<<dim3(BB / 128, DD / 128), 512, 0, stream>>>(
            wbf, Ub + (size_t)i * EE * DD * RR, inputs, xb, bias + (size_t)i * DD,
            out, i == LL - 1);
    }
}

// Round 4
// 279.058 us; speedup vs baseline: 1.6057x; 1.1659x over previous
//
#include <hip/hip_runtime.h>
#include <math.h>

#define BB 16384
#define DD 1024
#define RR 64
#define EE 4
#define ER 256   // EE*RR
#define LL 3

#define LDM 72   // mix-phase Tt stride

typedef __bf16 bf16x8 __attribute__((ext_vector_type(8)));
typedef float f32x4 __attribute__((ext_vector_type(4)));
typedef unsigned short us;

static __device__ inline us f2b(float f) {   // RNE f32->bf16
    union { float f; unsigned u; } c; c.f = f;
    return (us)((c.u + 0x7FFF + ((c.u >> 16) & 1)) >> 16);
}
static __device__ inline float b2f(us v) {
    union { unsigned u; float f; } c; c.u = ((unsigned)v) << 16;
    return c.f;
}
static __device__ inline float fast_tanh(float x) {
    float t = __expf(2.f * x);               // inf/0 at extremes -> +-1 exactly
    return 1.f - 2.f / (t + 1.f);
}
// async global->LDS, 16B/lane; dst is wave-uniform base, HW writes lane i at base+i*16
static __device__ __forceinline__ void ld_lds16(const us* g, us* l) {
    __builtin_amdgcn_global_load_lds((const __attribute__((address_space(1))) void*)g,
                                     (__attribute__((address_space(3))) void*)l, 16, 0, 0);
}

// generic f32 -> bf16 (4 elems/thread)
__global__ __launch_bounds__(256) void convF2B(const float* __restrict__ s, us* __restrict__ d) {
    int f = (blockIdx.x * 256 + threadIdx.x) * 4;
    float4 v = *(const float4*)&s[f];
    *(ushort4*)&d[f] = make_ushort4(f2b(v.x), f2b(v.y), f2b(v.z), f2b(v.w));
}
// V [le][d][r] f32 -> Vt [le][r][d] bf16
__global__ __launch_bounds__(256) void convV(const float* __restrict__ V, us* __restrict__ Vt) {
    const int le = blockIdx.x;
    const int d0 = blockIdx.y * 64;
    __shared__ float t[64 * 65];
    const int tid = threadIdx.x;
    const float* Vb = V + (size_t)le * DD * RR;
    #pragma unroll
    for (int p = 0; p < 4; ++p) {
        int f = tid + p * 256; int dd = f >> 4; int c = (f & 15) * 4;
        float4 v = *(const float4*)&Vb[(size_t)(d0 + dd) * RR + c];
        t[dd * 65 + c + 0] = v.x; t[dd * 65 + c + 1] = v.y;
        t[dd * 65 + c + 2] = v.z; t[dd * 65 + c + 3] = v.w;
    }
    __syncthreads();
    int r = tid >> 2, dg = (tid & 3) * 16;
    us o[16];
    #pragma unroll
    for (int k = 0; k < 16; ++k) o[k] = f2b(t[(dg + k) * 65 + r]);
    us* dst = Vt + (size_t)le * RR * DD + (size_t)r * DD + d0 + dg;
    #pragma unroll
    for (int q = 0; q < 4; ++q) *(ushort4*)&dst[q * 4] = *(ushort4*)&o[q * 4];
}

// K1 (all experts + fused gating): 512 thr, 8 waves: wave = (h = wave>>2 b-half, e = wave&3).
// 4 LDS buffers, 3-deep prefetch, ONE barrier per K-iter. Per tile each wave issues a
// uniform DMA count (waves 0-3: 2 Av + 1 Bx = 3; waves 4-7: 2 Av = 2) so counted vmcnt
// works per-wave: steady wait = 2 tiles in flight -> vmcnt(6)/vmcnt(4).
// Granule layout: g = row*4 + slot (16B each); source k-chunk = slot ^ ((row&15)>>1 & 3);
// read slot sA = quad ^ ((l15>>1)&3) -> linear DMA dst, coalesced src, ~2-way LDS reads.
__global__ __launch_bounds__(512, 2) void gemm1_fused(const us* __restrict__ xs,
                                                      const us* __restrict__ Vt,
                                                      const us* __restrict__ Ce,
                                                      const us* __restrict__ gwb,
                                                      us* __restrict__ w) {
    const int row0 = blockIdx.x * 64;
    const int tid = threadIdx.x;
    const int lane = tid & 63, wave = tid >> 6;
    const int l15 = lane & 15, quad = lane >> 4;
    const int e = wave & 3, h = wave >> 2;
    const int e64 = e * 64;

    __shared__ __align__(16) union {
        struct { us buf[4][10240]; us gw[4096]; float gates[256]; } s;  // 80K + 8K + 1K
        us Tt[4][64 * LDM];                                             // 36K, aliases buf only
    } u;

    const int kcA  = (lane & 3) ^ ((lane >> 3) & 3);   // source k-chunk for my slot
    const int sA   = quad ^ ((l15 >> 1) & 3);          // read slot
    const int rsub = lane >> 2;                        // 0..15

    // gw once: granule = kc*4 + gw_row; wave covers kc = wave*16 + rsub, row = lane&3
    ld_lds16(gwb + (size_t)(lane & 3) * DD + (wave * 16 + rsub) * 8, &u.s.gw[wave * 512]);

    auto STAGE = [&](int bi, int k0) {
        us* bb = u.s.buf[bi];
        #pragma unroll
        for (int j = 0; j < 2; ++j) {                  // Av rows wave*32 + j*16 + rsub
            int row = wave * 32 + j * 16 + rsub;
            ld_lds16(Vt + (size_t)row * DD + k0 + kcA * 8, &bb[(wave * 32 + j * 16) * 32]);
        }
        if (wave < 4) {                                // Bx rows wave*16 + rsub
            int row = wave * 16 + rsub;
            ld_lds16(xs + (size_t)(row0 + row) * DD + k0 + kcA * 8, &bb[8192 + wave * 512]);
        }
    };

    f32x4 acc[4][2] = {};
    f32x4 accg = {};
    STAGE(0, 0); STAGE(1, 32); STAGE(2, 64);

    for (int t = 0; t < 32; ++t) {
        if (t < 30) {
            if (wave < 4) asm volatile("s_waitcnt vmcnt(6)" ::: "memory");
            else          asm volatile("s_waitcnt vmcnt(4)" ::: "memory");
        } else if (t == 30) {
            if (wave < 4) asm volatile("s_waitcnt vmcnt(3)" ::: "memory");
            else          asm volatile("s_waitcnt vmcnt(2)" ::: "memory");
        } else {
            asm volatile("s_waitcnt vmcnt(0)" ::: "memory");
        }
        __builtin_amdgcn_s_barrier();                  // tile t ready; compute(t-1) done everywhere
        if (t < 29) STAGE((t + 3) & 3, (t + 3) * 32);  // overwrites buf read at iter t-1: safe
        __builtin_amdgcn_sched_barrier(0);
        const us* bb = u.s.buf[t & 3];
        bf16x8 af[4], bfr[2];
        #pragma unroll
        for (int mt = 0; mt < 4; ++mt)
            af[mt] = *(const bf16x8*)&bb[(e64 + mt * 16 + l15) * 32 + sA * 8];
        #pragma unroll
        for (int nt = 0; nt < 2; ++nt)
            bfr[nt] = *(const bf16x8*)&bb[8192 + (h * 32 + nt * 16 + l15) * 32 + sA * 8];
        #pragma unroll
        for (int mt = 0; mt < 4; ++mt)
            #pragma unroll
            for (int nt = 0; nt < 2; ++nt)
                acc[mt][nt] = __builtin_amdgcn_mfma_f32_16x16x32_bf16(af[mt], bfr[nt], acc[mt][nt], 0, 0, 0);
        if (wave < 4) {   // gate logits ride along (b = wave*16+l15, rows 0-3 = experts)
            bf16x8 bfrg = *(const bf16x8*)&bb[8192 + (wave * 16 + l15) * 32 + sA * 8];
            bf16x8 afg  = *(const bf16x8*)&u.s.gw[(t * 4 + quad) * 32 + (l15 & 3) * 8];
            accg = __builtin_amdgcn_mfma_f32_16x16x32_bf16(afg, bfrg, accg, 0, 0, 0);
        }
    }
    __builtin_amdgcn_s_barrier();                      // all buf reads done before Tt alias writes
    __builtin_amdgcn_sched_barrier(0);

    // tanh -> Tt_e[b][r] bf16 (each wave writes only its own (e,h) region)
    us* Tt = u.Tt[e];
    #pragma unroll
    for (int mt = 0; mt < 4; ++mt)
        #pragma unroll
        for (int nt = 0; nt < 2; ++nt) {
            int b = h * 32 + nt * 16 + l15;
            us o[4];
            #pragma unroll
            for (int i = 0; i < 4; ++i) o[i] = f2b(fast_tanh(acc[mt][nt][i]));
            *(ushort4*)&Tt[b * LDM + mt * 16 + quad * 4] = *(ushort4*)o;
        }
    if (wave < 4 && quad == 0) {   // accg rows 0-3 = logits e0..e3 for b = wave*16+l15
        float l0 = accg[0], l1 = accg[1], l2 = accg[2], l3 = accg[3];
        float m = fmaxf(fmaxf(l0, l1), fmaxf(l2, l3));
        float g0 = __expf(l0 - m), g1 = __expf(l1 - m);
        float g2 = __expf(l2 - m), g3 = __expf(l3 - m);
        float inv = 1.f / (g0 + g1 + g2 + g3);
        int b = wave * 16 + l15;
        u.s.gates[0 * 64 + b] = g0 * inv; u.s.gates[1 * 64 + b] = g1 * inv;
        u.s.gates[2 * 64 + b] = g2 * inv; u.s.gates[3 * 64 + b] = g3 * inv;
    }
    __syncthreads();

    // t2 = tanh(C_e @ t1); C-frags direct from global bf16 (L2-hot)
    const us* Cb = Ce + (size_t)e * RR * RR;
    f32x4 acc2[4][2] = {};
    #pragma unroll
    for (int ks = 0; ks < 2; ++ks) {
        bf16x8 af2[4], bf2[2];
        #pragma unroll
        for (int mt = 0; mt < 4; ++mt)
            af2[mt] = *(const bf16x8*)&Cb[(size_t)(mt * 16 + l15) * RR + ks * 32 + quad * 8];
        #pragma unroll
        for (int nt = 0; nt < 2; ++nt)
            bf2[nt] = *(const bf16x8*)&Tt[(h * 32 + nt * 16 + l15) * LDM + ks * 32 + quad * 8];
        #pragma unroll
        for (int mt = 0; mt < 4; ++mt)
            #pragma unroll
            for (int nt = 0; nt < 2; ++nt)
                acc2[mt][nt] = __builtin_amdgcn_mfma_f32_16x16x32_bf16(af2[mt], bf2[nt], acc2[mt][nt], 0, 0, 0);
    }
    #pragma unroll
    for (int mt = 0; mt < 4; ++mt)
        #pragma unroll
        for (int nt = 0; nt < 2; ++nt) {
            int b = h * 32 + nt * 16 + l15;
            float g = u.s.gates[e64 + b];
            us o[4];
            #pragma unroll
            for (int i = 0; i < 4; ++i) o[i] = f2b(g * fast_tanh(acc2[mt][nt][i]));
            *(ushort4*)&w[(size_t)(row0 + b) * ER + e64 + mt * 16 + quad * 4] = *(ushort4*)o;
        }
}

// K2: D[d][b] = U . w^T ; res = x0b*(D+bias) + xl. 512 thr, tile 128d x 128b.
// GEMM via swizzled-src global_load_lds dbuf + counted vmcnt. Epilogue: acc -> LDS
// (XOR-slot swizzle) in two 64-d passes, then each thread owns 16 contiguous d of one
// row -> fully coalesced 128B-per-row global reads (x0b, xl) and writes (xb/out).
__global__ __launch_bounds__(512, 4) void gemm2_combine(const us* __restrict__ w,
                                                        const us* __restrict__ Ub,
                                                        const us* __restrict__ x0b,
                                                        const us* __restrict__ xls,
                                                        us* __restrict__ xbo,
                                                        const float* __restrict__ biasl,
                                                        float* __restrict__ out, int last) {
    const int row0 = blockIdx.x * 128;     // b
    const int d0 = blockIdx.y * 128;       // d
    __shared__ __align__(16) union { us stage[2][8192]; float smf[8192]; } su;  // 32 KB
    const int tid = threadIdx.x;
    const int lane = tid & 63, wave = tid >> 6;
    const int bh = wave & 1, dh = wave >> 1;
    const int l15 = lane & 15, quad = lane >> 4;

    const int kcA = (lane & 3) ^ ((lane >> 3) & 3);
    const int sA  = quad ^ ((l15 >> 1) & 3);

    auto STAGE = [&](int bi, int s) {
        int e = s >> 1, r0q = (s & 1) * 32;
        us* bb = su.stage[bi];
        int row = wave * 16 + (lane >> 2);            // 0..127
        ld_lds16(Ub + ((size_t)e * DD + d0 + row) * RR + r0q + kcA * 8, &bb[wave * 512]);
        ld_lds16(w + (size_t)(row0 + row) * ER + e * 64 + r0q + kcA * 8, &bb[4096 + wave * 512]);
    };

    f32x4 acc[2][4] = {};
    STAGE(0, 0);
    for (int t = 0; t < 8; ++t) {
        __builtin_amdgcn_s_barrier();
        if (t < 7) {
            STAGE((t + 1) & 1, t + 1);
            asm volatile("s_waitcnt vmcnt(2)" ::: "memory");
        } else {
            asm volatile("s_waitcnt vmcnt(0)" ::: "memory");
        }
        __builtin_amdgcn_s_barrier();
        __builtin_amdgcn_sched_barrier(0);
        const us* bb = su.stage[t & 1];
        bf16x8 af[2], bfr[4];
        #pragma unroll
        for (int mt = 0; mt < 2; ++mt)
            af[mt] = *(const bf16x8*)&bb[(dh * 32 + mt * 16 + l15) * 32 + sA * 8];
        #pragma unroll
        for (int nt = 0; nt < 4; ++nt)
            bfr[nt] = *(const bf16x8*)&bb[4096 + (bh * 64 + nt * 16 + l15) * 32 + sA * 8];
        #pragma unroll
        for (int mt = 0; mt < 2; ++mt)
            #pragma unroll
            for (int nt = 0; nt < 4; ++nt)
                acc[mt][nt] = __builtin_amdgcn_mfma_f32_16x16x32_bf16(af[mt], bfr[nt], acc[mt][nt], 0, 0, 0);
    }

    // ---- epilogue: two passes over d (64 each) through LDS transpose ----
    const int erow = tid >> 2;          // 0..127 b-local
    const int ec   = tid & 3;           // 16-elem d-chunk within pass
    const size_t gb = (size_t)(row0 + erow) * DD + d0;
    #pragma unroll
    for (int p = 0; p < 2; ++p) {
        const int doff = p * 64 + ec * 16;
        uint xu[8], lu[8];              // issue global loads early (overlap barriers)
        *(uint4*)&xu[0] = *(const uint4*)&x0b[gb + doff];
        *(uint4*)&xu[4] = *(const uint4*)&x0b[gb + doff + 8];
        *(uint4*)&lu[0] = *(const uint4*)&xls[gb + doff];
        *(uint4*)&lu[4] = *(const uint4*)&xls[gb + doff + 8];
        float bf[16];
        *(float4*)&bf[0]  = *(const float4*)&biasl[d0 + doff];
        *(float4*)&bf[4]  = *(const float4*)&biasl[d0 + doff + 4];
        *(float4*)&bf[8]  = *(const float4*)&biasl[d0 + doff + 8];
        *(float4*)&bf[12] = *(const float4*)&biasl[d0 + doff + 12];
        __syncthreads();                // stage reads (p=0) / prev-pass reads (p=1) done
        if ((dh >> 1) == p) {           // waves owning this d-half write acc -> smf
            #pragma unroll
            for (int mt = 0; mt < 2; ++mt)
                #pragma unroll
                for (int nt = 0; nt < 4; ++nt) {
                    int r = bh * 64 + nt * 16 + l15;
                    int s = (dh & 1) * 8 + mt * 4 + quad;
                    *(f32x4*)&su.smf[r * 64 + ((s ^ (r & 15)) << 2)] = acc[mt][nt];
                }
        }
        __syncthreads();
        float o[16];
        #pragma unroll
        for (int j = 0; j < 4; ++j) {
            int s = ec * 4 + j;
            float4 a = *(const float4*)&su.smf[erow * 64 + ((s ^ (erow & 15)) << 2)];
            #pragma unroll
            for (int i = 0; i < 4; ++i) {
                int k = j * 4 + i;
                float av = (i == 0) ? a.x : (i == 1) ? a.y : (i == 2) ? a.z : a.w;
                uint uu = xu[k >> 1], ll = lu[k >> 1];
                float xv = b2f((k & 1) ? (us)(uu >> 16) : (us)(uu & 0xffff));
                float xl = b2f((k & 1) ? (us)(ll >> 16) : (us)(ll & 0xffff));
                o[k] = xv * (av + bf[k]) + xl;
            }
        }
        if (last) {
            *(float4*)&out[gb + doff]      = *(float4*)&o[0];
            *(float4*)&out[gb + doff + 4]  = *(float4*)&o[4];
            *(float4*)&out[gb + doff + 8]  = *(float4*)&o[8];
            *(float4*)&out[gb + doff + 12] = *(float4*)&o[12];
        } else {
            us ob[16];
            #pragma unroll
            for (int k = 0; k < 16; ++k) ob[k] = f2b(o[k]);
            *(uint4*)&xbo[gb + doff]     = *(uint4*)&ob[0];
            *(uint4*)&xbo[gb + doff + 8] = *(uint4*)&ob[8];
        }
    }
}

extern "C" void kernel_launch(void* const* d_in, const int* in_sizes, int n_in,
                              void* d_out, int out_size, void* d_ws, size_t ws_size,
                              hipStream_t stream) {
    const float* inputs = (const float*)d_in[0];
    const float* U      = (const float*)d_in[1];
    const float* V      = (const float*)d_in[2];
    const float* C      = (const float*)d_in[3];
    const float* gw     = (const float*)d_in[4];
    const float* bias   = (const float*)d_in[5];
    float* out = (float*)d_out;

    // ws: xb0 33.55 | xb 33.55 | w 8.39 | gwb 8KB | Vt 1.57 | Ub 1.57 | Cb 0.10  = ~78.7 MB
    us* xb0 = (us*)d_ws;                         // bf16(inputs), const across layers
    us* xb  = xb0 + (size_t)BB * DD;             // residual stream (written layer 0)
    us* wbf = xb + (size_t)BB * DD;
    us* gwb = wbf + (size_t)BB * ER;
    us* Vt  = gwb + (size_t)EE * DD;
    us* Ub  = Vt + (size_t)LL * EE * RR * DD;
    us* Cb  = Ub + (size_t)LL * EE * DD * RR;

    convF2B<<<dim3(BB * DD / 1024), 256, 0, stream>>>(inputs, xb0);
    convF2B<<<dim3(LL * EE * DD * RR / 1024), 256, 0, stream>>>(U, Ub);
    convF2B<<<dim3(LL * EE * RR * RR / 1024), 256, 0, stream>>>(C, Cb);
    convF2B<<<dim3(EE * DD / 1024), 256, 0, stream>>>(gw, gwb);
    convV<<<dim3(LL * EE, DD / 64), 256, 0, stream>>>(V, Vt);

    for (int i = 0; i < LL; ++i) {
        const us* xs = (i == 0) ? xb0 : xb;      // stream source
        gemm1_fused<<<dim3(BB / 64), 512, 0, stream>>>(
            xs, Vt + (size_t)i * EE * RR * DD, Cb + (size_t)i * EE * RR * RR, gwb, wbf);
        gemm2_combine<<<dim3(BB / 128, DD / 128), 512, 0, stream>>>(
            wbf, Ub + (size_t)i * EE * DD * RR, xb0, xs, xb, bias + (size_t)i * DD,
            out, i == LL - 1);
    }
}

// Round 5
// 278.693 us; speedup vs baseline: 1.6078x; 1.0013x over previous
//
#include <hip/hip_runtime.h>
#include <math.h>

#define BB 16384
#define DD 1024
#define RR 64
#define EE 4
#define ER 256   // EE*RR
#define LL 3

#define LDM 72   // mix-phase Tt stride

typedef __bf16 bf16x8 __attribute__((ext_vector_type(8)));
typedef float f32x4 __attribute__((ext_vector_type(4)));
typedef unsigned short us;

static __device__ inline us f2b(float f) {   // RNE f32->bf16
    union { float f; unsigned u; } c; c.f = f;
    return (us)((c.u + 0x7FFF + ((c.u >> 16) & 1)) >> 16);
}
static __device__ inline float b2f(us v) {
    union { unsigned u; float f; } c; c.u = ((unsigned)v) << 16;
    return c.f;
}
static __device__ inline float fast_tanh(float x) {
    float t = __expf(2.f * x);               // inf/0 at extremes -> +-1 exactly
    return 1.f - 2.f / (t + 1.f);
}
// async global->LDS, 16B/lane; dst is wave-uniform base, HW writes lane i at base+i*16
static __device__ __forceinline__ void ld_lds16(const us* g, us* l) {
    __builtin_amdgcn_global_load_lds((const __attribute__((address_space(1))) void*)g,
                                     (__attribute__((address_space(3))) void*)l, 16, 0, 0);
}

// generic f32 -> bf16 (4 elems/thread)
__global__ __launch_bounds__(256) void convF2B(const float* __restrict__ s, us* __restrict__ d) {
    int f = (blockIdx.x * 256 + threadIdx.x) * 4;
    float4 v = *(const float4*)&s[f];
    *(ushort4*)&d[f] = make_ushort4(f2b(v.x), f2b(v.y), f2b(v.z), f2b(v.w));
}
// V [le][d][r] f32 -> Vt [le][r][d] bf16
__global__ __launch_bounds__(256) void convV(const float* __restrict__ V, us* __restrict__ Vt) {
    const int le = blockIdx.x;
    const int d0 = blockIdx.y * 64;
    __shared__ float t[64 * 65];
    const int tid = threadIdx.x;
    const float* Vb = V + (size_t)le * DD * RR;
    #pragma unroll
    for (int p = 0; p < 4; ++p) {
        int f = tid + p * 256; int dd = f >> 4; int c = (f & 15) * 4;
        float4 v = *(const float4*)&Vb[(size_t)(d0 + dd) * RR + c];
        t[dd * 65 + c + 0] = v.x; t[dd * 65 + c + 1] = v.y;
        t[dd * 65 + c + 2] = v.z; t[dd * 65 + c + 3] = v.w;
    }
    __syncthreads();
    int r = tid >> 2, dg = (tid & 3) * 16;
    us o[16];
    #pragma unroll
    for (int k = 0; k < 16; ++k) o[k] = f2b(t[(dg + k) * 65 + r]);
    us* dst = Vt + (size_t)le * RR * DD + (size_t)r * DD + d0 + dg;
    #pragma unroll
    for (int q = 0; q < 4; ++q) *(ushort4*)&dst[q * 4] = *(ushort4*)&o[q * 4];
}

// Whole layer fused, block = 64 b-rows, 512 thr (8 waves). See design notes above.
__global__ __launch_bounds__(512, 2) void layer_fused(const us* __restrict__ xs,
                                                      const us* __restrict__ Vt,
                                                      const us* __restrict__ Ce,
                                                      const us* __restrict__ gwb,
                                                      const us* __restrict__ x0b,
                                                      const us* __restrict__ Ub,
                                                      us* __restrict__ xbo,
                                                      const float* __restrict__ biasl,
                                                      float* __restrict__ out, int last) {
    const int row0 = blockIdx.x * 64;
    const int tid = threadIdx.x;
    const int lane = tid & 63, wave = tid >> 6;
    const int l15 = lane & 15, quad = lane >> 4;
    const int e = wave & 3, h = wave >> 2;
    const int e64 = e * 64;

    __shared__ __align__(16) union {
        struct { us buf[4][10240]; us gw[4096]; float gates[256]; } s;  // 89 KB
        us Tt[4][64 * LDM];                                             // 36 KB
        struct { us wlds[64 * 256]; float smf[8][1024]; } p2;           // 32 + 32 KB
    } u;

    const int kcA  = (lane & 3) ^ ((lane >> 3) & 3);   // source k-chunk for my slot
    const int sA   = quad ^ ((l15 >> 1) & 3);          // read slot
    const int rsub = lane >> 2;                        // 0..15

    // gw once: granule = kc*4 + gw_row; wave covers kc = wave*16 + rsub, row = lane&3
    ld_lds16(gwb + (size_t)(lane & 3) * DD + (wave * 16 + rsub) * 8, &u.s.gw[wave * 512]);

    auto STAGE = [&](int bi, int k0) {
        us* bb = u.s.buf[bi];
        #pragma unroll
        for (int j = 0; j < 2; ++j) {                  // Av rows wave*32 + j*16 + rsub
            int row = wave * 32 + j * 16 + rsub;
            ld_lds16(Vt + (size_t)row * DD + k0 + kcA * 8, &bb[(wave * 32 + j * 16) * 32]);
        }
        if (wave < 4) {                                // Bx rows wave*16 + rsub
            int row = wave * 16 + rsub;
            ld_lds16(xs + (size_t)(row0 + row) * DD + k0 + kcA * 8, &bb[8192 + wave * 512]);
        }
    };

    f32x4 acc[4][2] = {};
    f32x4 accg = {};
    STAGE(0, 0); STAGE(1, 32); STAGE(2, 64);

    for (int t = 0; t < 32; ++t) {
        if (t < 30) {
            if (wave < 4) asm volatile("s_waitcnt vmcnt(6)" ::: "memory");
            else          asm volatile("s_waitcnt vmcnt(4)" ::: "memory");
        } else if (t == 30) {
            if (wave < 4) asm volatile("s_waitcnt vmcnt(3)" ::: "memory");
            else          asm volatile("s_waitcnt vmcnt(2)" ::: "memory");
        } else {
            asm volatile("s_waitcnt vmcnt(0)" ::: "memory");
        }
        __builtin_amdgcn_s_barrier();                  // tile t ready; compute(t-1) done everywhere
        if (t < 29) STAGE((t + 3) & 3, (t + 3) * 32);  // overwrites buf read at iter t-1: safe
        __builtin_amdgcn_sched_barrier(0);
        const us* bb = u.s.buf[t & 3];
        bf16x8 af[4], bfr[2];
        #pragma unroll
        for (int mt = 0; mt < 4; ++mt)
            af[mt] = *(const bf16x8*)&bb[(e64 + mt * 16 + l15) * 32 + sA * 8];
        #pragma unroll
        for (int nt = 0; nt < 2; ++nt)
            bfr[nt] = *(const bf16x8*)&bb[8192 + (h * 32 + nt * 16 + l15) * 32 + sA * 8];
        #pragma unroll
        for (int mt = 0; mt < 4; ++mt)
            #pragma unroll
            for (int nt = 0; nt < 2; ++nt)
                acc[mt][nt] = __builtin_amdgcn_mfma_f32_16x16x32_bf16(af[mt], bfr[nt], acc[mt][nt], 0, 0, 0);
        if (wave < 4) {   // gate logits ride along (b = wave*16+l15, rows 0-3 = experts)
            bf16x8 bfrg = *(const bf16x8*)&bb[8192 + (wave * 16 + l15) * 32 + sA * 8];
            bf16x8 afg  = *(const bf16x8*)&u.s.gw[(t * 4 + quad) * 32 + (l15 & 3) * 8];
            accg = __builtin_amdgcn_mfma_f32_16x16x32_bf16(afg, bfrg, accg, 0, 0, 0);
        }
    }
    __builtin_amdgcn_s_barrier();                      // all buf reads done before Tt alias writes
    __builtin_amdgcn_sched_barrier(0);

    // tanh -> Tt_e[b][r] bf16 (each wave writes only its own (e,h) region)
    {
        us* Tt = u.Tt[e];
        #pragma unroll
        for (int mt = 0; mt < 4; ++mt)
            #pragma unroll
            for (int nt = 0; nt < 2; ++nt) {
                int b = h * 32 + nt * 16 + l15;
                us o[4];
                #pragma unroll
                for (int i = 0; i < 4; ++i) o[i] = f2b(fast_tanh(acc[mt][nt][i]));
                *(ushort4*)&Tt[b * LDM + mt * 16 + quad * 4] = *(ushort4*)o;
            }
    }
    if (wave < 4 && quad == 0) {   // accg rows 0-3 = logits e0..e3 for b = wave*16+l15
        float l0 = accg[0], l1 = accg[1], l2 = accg[2], l3 = accg[3];
        float m = fmaxf(fmaxf(l0, l1), fmaxf(l2, l3));
        float g0 = __expf(l0 - m), g1 = __expf(l1 - m);
        float g2 = __expf(l2 - m), g3 = __expf(l3 - m);
        float inv = 1.f / (g0 + g1 + g2 + g3);
        int b = wave * 16 + l15;
        u.s.gates[0 * 64 + b] = g0 * inv; u.s.gates[1 * 64 + b] = g1 * inv;
        u.s.gates[2 * 64 + b] = g2 * inv; u.s.gates[3 * 64 + b] = g3 * inv;
    }
    __syncthreads();

    // t2 = tanh(C_e @ t1); C-frags direct from global bf16 (L2-hot)
    const us* Cb = Ce + (size_t)e * RR * RR;
    f32x4 acc2[4][2] = {};
    #pragma unroll
    for (int ks = 0; ks < 2; ++ks) {
        bf16x8 af2[4], bf2[2];
        #pragma unroll
        for (int mt = 0; mt < 4; ++mt)
            af2[mt] = *(const bf16x8*)&Cb[(size_t)(mt * 16 + l15) * RR + ks * 32 + quad * 8];
        #pragma unroll
        for (int nt = 0; nt < 2; ++nt)
            bf2[nt] = *(const bf16x8*)&u.Tt[e][(h * 32 + nt * 16 + l15) * LDM + ks * 32 + quad * 8];
        #pragma unroll
        for (int mt = 0; mt < 4; ++mt)
            #pragma unroll
            for (int nt = 0; nt < 2; ++nt)
                acc2[mt][nt] = __builtin_amdgcn_mfma_f32_16x16x32_bf16(af2[mt], bf2[nt], acc2[mt][nt], 0, 0, 0);
    }
    __syncthreads();               // ALL Tt reads done before wlds (aliases Tt/buf) writes

    // w = g * tanh(acc2) -> wlds[b][col] with 16B-chunk XOR swizzle: cc' = cc ^ (b&7)
    #pragma unroll
    for (int mt = 0; mt < 4; ++mt)
        #pragma unroll
        for (int nt = 0; nt < 2; ++nt) {
            int b = h * 32 + nt * 16 + l15;
            float g = u.s.gates[e64 + b];          // gates @88KB: disjoint from wlds
            us o[4];
            #pragma unroll
            for (int i = 0; i < 4; ++i) o[i] = f2b(g * fast_tanh(acc2[mt][nt][i]));
            int col = e64 + mt * 16 + quad * 4;
            int cc = col >> 3, off = col & 7;
            *(ushort4*)&u.p2.wlds[b * 256 + ((cc ^ (b & 7)) << 3) + off] = *(ushort4*)o;
        }
    __syncthreads();               // wlds ready; phase 2 is barrier-free

    // ---- phase 2: D[d][b] = U . w^T; wave owns 64 d per pass, all 64 b ----
    const int bl = lane >> 2, dc3 = lane & 3;
    #pragma unroll 1
    for (int p = 0; p < 2; ++p) {
        const int dw = p * 512 + wave * 64;
        f32x4 pac[4][4] = {};
        #pragma unroll
        for (int s = 0; s < 8; ++s) {
            int e2 = s >> 1, r0 = (s & 1) * 32;
            bf16x8 af[4], bfr[4];
            #pragma unroll
            for (int mt = 0; mt < 4; ++mt) {
                int d = dw + mt * 16 + l15;
                af[mt] = *(const bf16x8*)&Ub[((size_t)e2 * DD + d) * RR + r0 + quad * 8];
            }
            #pragma unroll
            for (int nt = 0; nt < 4; ++nt) {
                int b = nt * 16 + l15;
                int cc = e2 * 8 + (r0 >> 3) + quad;
                bfr[nt] = *(const bf16x8*)&u.p2.wlds[b * 256 + ((cc ^ (b & 7)) << 3)];
            }
            #pragma unroll
            for (int mt = 0; mt < 4; ++mt)
                #pragma unroll
                for (int nt = 0; nt < 4; ++nt)
                    pac[mt][nt] = __builtin_amdgcn_mfma_f32_16x16x32_bf16(af[mt], bfr[nt], pac[mt][nt], 0, 0, 0);
        }
        // epilogue: bias for my 16 d (nt-invariant), then per-nt transpose + combine
        const int dg = dw + dc3 * 16;
        float bfv[16];
        *(float4*)&bfv[0]  = *(const float4*)&biasl[dg];
        *(float4*)&bfv[4]  = *(const float4*)&biasl[dg + 4];
        *(float4*)&bfv[8]  = *(const float4*)&biasl[dg + 8];
        *(float4*)&bfv[12] = *(const float4*)&biasl[dg + 12];
        float* smf = u.p2.smf[wave];   // wave-private 4 KB
        #pragma unroll
        for (int nt = 0; nt < 4; ++nt) {
            #pragma unroll
            for (int mt = 0; mt < 4; ++mt) {
                int ch = (mt * 4 + quad) ^ (l15 & 7);
                *(f32x4*)&smf[l15 * 64 + ch * 4] = pac[mt][nt];
            }
            asm volatile("s_waitcnt lgkmcnt(0)" ::: "memory");
            __builtin_amdgcn_sched_barrier(0);
            const int brow = row0 + nt * 16 + bl;
            const size_t gb = (size_t)brow * DD + dg;
            uint xu[8], lu[8];
            *(uint4*)&xu[0] = *(const uint4*)&x0b[gb];
            *(uint4*)&xu[4] = *(const uint4*)&x0b[gb + 8];
            *(uint4*)&lu[0] = *(const uint4*)&xs[gb];
            *(uint4*)&lu[4] = *(const uint4*)&xs[gb + 8];
            float o[16];
            #pragma unroll
            for (int j = 0; j < 4; ++j) {
                int ch = (dc3 * 4 + j) ^ (bl & 7);
                float4 a = *(const float4*)&smf[bl * 64 + ch * 4];
                #pragma unroll
                for (int i = 0; i < 4; ++i) {
                    int k = j * 4 + i;
                    float av = (i == 0) ? a.x : (i == 1) ? a.y : (i == 2) ? a.z : a.w;
                    uint uu = xu[k >> 1], ll = lu[k >> 1];
                    float xv = b2f((k & 1) ? (us)(uu >> 16) : (us)(uu & 0xffff));
                    float xl = b2f((k & 1) ? (us)(ll >> 16) : (us)(ll & 0xffff));
                    o[k] = xv * (av + bfv[k]) + xl;
                }
            }
            if (last) {
                *(float4*)&out[gb]      = *(float4*)&o[0];
                *(float4*)&out[gb + 4]  = *(float4*)&o[4];
                *(float4*)&out[gb + 8]  = *(float4*)&o[8];
                *(float4*)&out[gb + 12] = *(float4*)&o[12];
            } else {
                us ob[16];
                #pragma unroll
                for (int k = 0; k < 16; ++k) ob[k] = f2b(o[k]);
                *(uint4*)&xbo[gb]     = *(uint4*)&ob[0];
                *(uint4*)&xbo[gb + 8] = *(uint4*)&ob[8];
            }
            asm volatile("s_waitcnt lgkmcnt(0)" ::: "memory");   // smf reads done before next nt writes
            __builtin_amdgcn_sched_barrier(0);
        }
    }
}

extern "C" void kernel_launch(void* const* d_in, const int* in_sizes, int n_in,
                              void* d_out, int out_size, void* d_ws, size_t ws_size,
                              hipStream_t stream) {
    const float* inputs = (const float*)d_in[0];
    const float* U      = (const float*)d_in[1];
    const float* V      = (const float*)d_in[2];
    const float* C      = (const float*)d_in[3];
    const float* gw     = (const float*)d_in[4];
    const float* bias   = (const float*)d_in[5];
    float* out = (float*)d_out;

    // ws: xb0 33.55 | xb 33.55 | gwb 8KB | Vt 1.57 | Ub 1.57 | Cb 0.10  = ~70.3 MB
    us* xb0 = (us*)d_ws;                         // bf16(inputs), const across layers
    us* xb  = xb0 + (size_t)BB * DD;             // residual stream
    us* gwb = xb + (size_t)BB * DD;
    us* Vt  = gwb + (size_t)EE * DD;
    us* Ub  = Vt + (size_t)LL * EE * RR * DD;
    us* Cb  = Ub + (size_t)LL * EE * DD * RR;

    convF2B<<<dim3(BB * DD / 1024), 256, 0, stream>>>(inputs, xb0);
    convF2B<<<dim3(LL * EE * DD * RR / 1024), 256, 0, stream>>>(U, Ub);
    convF2B<<<dim3(LL * EE * RR * RR / 1024), 256, 0, stream>>>(C, Cb);
    convF2B<<<dim3(EE * DD / 1024), 256, 0, stream>>>(gw, gwb);
    convV<<<dim3(LL * EE, DD / 64), 256, 0, stream>>>(V, Vt);

    for (int i = 0; i < LL; ++i) {
        const us* xs = (i == 0) ? xb0 : xb;
        layer_fused<<<dim3(BB / 64), 512, 0, stream>>>(
            xs, Vt + (size_t)i * EE * RR * DD, Cb + (size_t)i * EE * RR * RR, gwb,
            xb0, Ub + (size_t)i * EE * DD * RR, xb, bias + (size_t)i * DD,
            out, i == LL - 1);
    }
}